// Round 7
// baseline (562.626 us; speedup 1.0000x reference)
//
#include <hip/hip_runtime.h>
#include <cstdint>
#include <cstddef>

// ---------------------------------------------------------------------------
// CircularSplineLayer pipeline:
//  k_stats          global sum/sumsq of x_passive; also ldout = ldin (free)
//  k_prep           xn -> bf16 [1024][4096]
//  k_transpose_cvt  f32 [K][N] -> bf16 [N][K], 256x128 tiles, XOR-swizzled LDS
//  k_gemm1          split-K=2 MFMA bf16, 4-deep LDS ring + counted vmcnt
//  k_gemm1b         combine partials + bias + tanh -> h bf16 [1024][512]
//  k_gemm2          MFMA 32x32x16 tile 256x96, single-buffer LDS (25600B),
//                   T14 issue-early split, DMA-source slot-swizzle
//                   (slot ^= (row>>1)&3 per 64B window; LDS dest linear,
//                   reader XORs back -> 32x32 frag reads at bank floor).
//                   XCD-chunked swizzle. Fused spline epilogue; log-density
//                   accumulated via device atomics (no part array/k_ldred).
// ---------------------------------------------------------------------------

typedef unsigned short u16;
typedef __bf16 bf16x8 __attribute__((ext_vector_type(8)));
typedef float f32x4 __attribute__((ext_vector_type(4)));
typedef float f32x16 __attribute__((ext_vector_type(16)));
typedef unsigned short u16x8 __attribute__((ext_vector_type(8)));
typedef unsigned short u16x4 __attribute__((ext_vector_type(4)));
typedef unsigned short u16x2 __attribute__((ext_vector_type(2)));

#define TWOPI_F 6.28318530717958647692f

static __device__ __forceinline__ u16 f32_to_bf16(float f){
  unsigned u = __builtin_bit_cast(unsigned, f);
  return (u16)((u + 0x7fffu + ((u >> 16) & 1u)) >> 16);   // RNE
}
static __device__ __forceinline__ void async16(void* lds, const void* g){
  // global->LDS DMA, 16B/lane; LDS dest = wave-uniform base + lane*16
  __builtin_amdgcn_global_load_lds((const __attribute__((address_space(1))) void*)g,
                                   (__attribute__((address_space(3))) void*)lds,
                                   16, 0, 0);
}
static __device__ __forceinline__ float rcpf(float x){ return __builtin_amdgcn_rcpf(x); }
static __device__ __forceinline__ float fast_tanh(float x){
  x = fminf(fmaxf(x, -15.f), 15.f);
  float e = __expf(2.f * x);
  return (e - 1.f) / (e + 1.f);
}
// clamp-free tanh: 1 - 2/(e^{2x}+1); inf-safe (rcp(inf)=0 -> 1, rcp(1)=1 -> -1)
static __device__ __forceinline__ float tanh_nc(float x){
  const float e2 = __expf(2.f * x);
  return 1.f - 2.f * rcpf(e2 + 1.f);
}
// exp(tanh(x)) fused, clamp-free
static __device__ __forceinline__ float exp_tanh(float x){
  const float e2 = __expf(2.f * x);
  const float u  = rcpf(e2 + 1.f);
  return __expf(1.f - 2.f * u);
}

// ---- global sum / sumsq of x_passive (4194304 f32); ldout init piggyback ----
__global__ void k_stats(const float* __restrict__ xp, float* __restrict__ stats,
                        const float* __restrict__ ldin, float* __restrict__ ldout){
  __shared__ float ss[4], sq[4];
  const int tid = threadIdx.x;
  if (tid == 0) ldout[blockIdx.x] = ldin[blockIdx.x];    // 1024 blocks == B
  const long gt = (long)blockIdx.x * 256 + tid;          // float4 index
  const float4* x4 = (const float4*)xp;
  float s = 0.f, q = 0.f;
  #pragma unroll
  for (int p = 0; p < 4; ++p){
    float4 v = x4[gt + (long)p * 262144];
    s += v.x + v.y + v.z + v.w;
    q += v.x*v.x + v.y*v.y + v.z*v.z + v.w*v.w;
  }
  #pragma unroll
  for (int off = 32; off; off >>= 1){
    s += __shfl_down(s, off);
    q += __shfl_down(q, off);
  }
  if ((tid & 63) == 0){ ss[tid>>6] = s; sq[tid>>6] = q; }
  __syncthreads();
  if (tid == 0){
    atomicAdd(stats,     ss[0]+ss[1]+ss[2]+ss[3]);
    atomicAdd(stats + 1, sq[0]+sq[1]+sq[2]+sq[3]);
  }
}

// ---- xn = (x - mean)*istd -> bf16 ----
__global__ void k_prep(const float* __restrict__ xp, const float* __restrict__ stats,
                       u16* __restrict__ xn){
  const long t = (long)blockIdx.x * 256 + threadIdx.x;   // 524288 threads, 8 elems each
  const float sum = stats[0], sq = stats[1];
  const float N = 4194304.f;
  const float mean = sum / N;
  const float istd = rsqrtf((sq - sum*sum/N) / (N - 1.f));  // ddof=1
  const float4* x4 = (const float4*)xp;
  const float4 a = x4[2*t], b = x4[2*t+1];
  u16x8 o;
  o[0]=f32_to_bf16((a.x-mean)*istd); o[1]=f32_to_bf16((a.y-mean)*istd);
  o[2]=f32_to_bf16((a.z-mean)*istd); o[3]=f32_to_bf16((a.w-mean)*istd);
  o[4]=f32_to_bf16((b.x-mean)*istd); o[5]=f32_to_bf16((b.y-mean)*istd);
  o[6]=f32_to_bf16((b.z-mean)*istd); o[7]=f32_to_bf16((b.w-mean)*istd);
  ((u16x8*)xn)[t] = o;
}

// ---- f32 [Kd][Nd] -> bf16 [Nd][Kd]; 256(k) x 128(n) tiles ----
// Store: k-pair P of row n lands at pair-position P ^ (sigma<<2), sigma=(n>>2)&7
// (an XOR on the pair-GROUP index P>>2). Read: pair-group lk is therefore at
// group-position lk ^ sigma. Global reads AND writes stay 512B-contiguous.
__global__ __launch_bounds__(256) void k_transpose_cvt(const float* __restrict__ in,
                                                       u16* __restrict__ out,
                                                       int Kd, int Nd){
  __shared__ __align__(16) u16 tT[128*256];
  const int tid = threadIdx.x;
  const long k0 = (long)blockIdx.x * 256, n0 = (long)blockIdx.y * 128;
  const int lam = tid & 31, g = tid >> 5;
  const int c = lam * 4;
  const int sig = (lam & 7) << 2;                 // (sigma)<<2, sigma=(n>>2)&7
  #pragma unroll
  for (int pass = 0; pass < 16; ++pass){
    const int P = pass*8 + g;                     // k-pair index 0..127
    const float4 f0 = *(const float4*)&in[(k0 + 2*P    )*Nd + n0 + c];
    const float4 f1 = *(const float4*)&in[(k0 + 2*P + 1)*Nd + n0 + c];
    const int pp = 2*(P ^ sig);
    *(u16x2*)&tT[(c    )*256 + pp] = u16x2{f32_to_bf16(f0.x), f32_to_bf16(f1.x)};
    *(u16x2*)&tT[(c + 1)*256 + pp] = u16x2{f32_to_bf16(f0.y), f32_to_bf16(f1.y)};
    *(u16x2*)&tT[(c + 2)*256 + pp] = u16x2{f32_to_bf16(f0.z), f32_to_bf16(f1.z)};
    *(u16x2*)&tT[(c + 3)*256 + pp] = u16x2{f32_to_bf16(f0.w), f32_to_bf16(f1.w)};
  }
  __syncthreads();
  const int w = tid >> 6, l = tid & 63;
  const int lh = l >> 5, lk = l & 31;
  #pragma unroll
  for (int it = 0; it < 16; ++it){
    const int n = (w << 5) + (it << 1) + lh;
    const int s2 = (n >> 2) & 7;                  // sigma (group-index XOR) — NOT <<2
    const u16x8 v = *(const u16x8*)&tT[n*256 + 8*(lk ^ s2)];
    *(u16x8*)&out[(n0 + n)*Kd + k0 + 8*lk] = v;
  }
}

// ---- GEMM1 split-K: partial = xn @ w1 over half of K. M=1024 N=512 ----
// 4-deep LDS ring, prefetch depth 2, counted vmcnt (2 DMA instrs/wave/stage).
__global__ __launch_bounds__(256, 2) void k_gemm1(
    const u16* __restrict__ xn,   // [1024][4096] bf16
    const u16* __restrict__ w1t,  // [512][4096] bf16 (n-major)
    float* __restrict__ pp)       // [2][1024][512] f32 partials
{
  __shared__ __align__(16) u16 sA[4][64*32];
  __shared__ __align__(16) u16 sB[4][64*32];
  const int tid = threadIdx.x, lane = tid & 63, w = tid >> 6;
  const int n0 = blockIdx.x << 6, m0 = blockIdx.y << 6;
  const int ks = blockIdx.z;
  const int wm = w >> 1, wn = w & 1;
  const int rA = lane >> 2, cA = (lane & 3) << 3;
  const int fr = lane & 15, fq = lane >> 4;
  const f32x4 z4 = {0.f, 0.f, 0.f, 0.f};
  f32x4 acc[2][2];
  #pragma unroll
  for (int i=0;i<2;i++){ acc[i][0] = z4; acc[i][1] = z4; }

  auto stage = [&](int kt){
    const int b = kt & 3;
    const int kofs = (ks << 11) + (kt << 5) + cA;
    async16(sA[b] + w*512, xn  + (long)(m0 + w*16 + rA)*4096 + kofs);
    async16(sB[b] + w*512, w1t + (long)(n0 + w*16 + rA)*4096 + kofs);
  };

  stage(0); stage(1);
  for (int kt = 0; kt < 64; ++kt){
    if (kt < 62){
      stage(kt + 2);
      asm volatile("s_waitcnt vmcnt(4)" ::: "memory");   // kt's 2 DMAs done
    } else if (kt == 62){
      asm volatile("s_waitcnt vmcnt(2)" ::: "memory");
    } else {
      asm volatile("s_waitcnt vmcnt(0)" ::: "memory");
    }
    __builtin_amdgcn_s_barrier();
    const int b = kt & 3;
    bf16x8 af[2], bfv[2];
    #pragma unroll
    for (int i=0;i<2;i++) af[i]  = *(const bf16x8*)(sA[b] + ((wm<<5) + i*16 + fr)*32 + (fq<<3));
    #pragma unroll
    for (int j=0;j<2;j++) bfv[j] = *(const bf16x8*)(sB[b] + ((wn<<5) + j*16 + fr)*32 + (fq<<3));
    #pragma unroll
    for (int i=0;i<2;i++)
      #pragma unroll
      for (int j=0;j<2;j++)
        acc[i][j] = __builtin_amdgcn_mfma_f32_16x16x32_bf16(af[i], bfv[j], acc[i][j], 0, 0, 0);
  }
  float* po = pp + ((size_t)ks << 19);
  #pragma unroll
  for (int i=0;i<2;i++)
    #pragma unroll
    for (int j=0;j<2;j++)
      #pragma unroll
      for (int r=0;r<4;r++){
        const int row = m0 + (wm<<5) + i*16 + (fq<<2) + r;   // C/D: row=(lane>>4)*4+reg
        const int col = n0 + (wn<<5) + j*16 + fr;            //      col=lane&15
        po[row*512 + col] = acc[i][j][r];
      }
}

// ---- combine split-K partials: h = tanh(p0+p1+b1) -> bf16 ----
__global__ void k_gemm1b(const float* __restrict__ pp, const float* __restrict__ b1,
                         u16* __restrict__ hb){
  const int t = blockIdx.x * 256 + threadIdx.x;    // 131072 float4 groups
  const float4 a = ((const float4*)pp)[t];
  const float4 b = ((const float4*)pp)[131072 + t];
  const float4 bb = ((const float4*)b1)[t & 127];
  u16x4 o;
  o[0] = f32_to_bf16(fast_tanh(a.x + b.x + bb.x));
  o[1] = f32_to_bf16(fast_tanh(a.y + b.y + bb.y));
  o[2] = f32_to_bf16(fast_tanh(a.z + b.z + bb.z));
  o[3] = f32_to_bf16(fast_tanh(a.w + b.w + bb.w));
  ((u16x4*)hb)[t] = o;
}

// ---- GEMM2 + spline epilogue: M=1024 N=98304 K=512, tile 256x96 ----
// 1-D grid 4096, bijective XCD-chunked swizzle: work = ((id&7)<<9)|(id>>3).
// 32x32x16 MFMA (12/kt/wave @8cy vs 24 @4.85 -> half the issue slots).
// Slot swizzle (rule #21 pattern c): DMA *global source* column slot is
// XORed with rho(row)=(row>>1)&3 per 64B window; LDS dest stays linear;
// reader XORs the slot back. Restores the 8-lanes/16B-group bank floor that
// a naive 32x32 frag read from [row][32k] would break (only 4/8 groups hit).
// T14 issue-early split per kt (as r6): vmcnt(0)+bar / ds_read+lgkm+bar /
// stage(kt+1) / MFMA.
__global__ __launch_bounds__(256, 2) void k_gemm2(
    const u16* __restrict__ hmat,   // [1024][512] bf16
    const u16* __restrict__ w2t,    // [98304][512] bf16 (n-major)
    const float* __restrict__ b2,
    const float* __restrict__ x_in, // [1024][4096]
    const float* __restrict__ phase,
    float* __restrict__ phi_out,    // [1024][4096]
    float* __restrict__ ld)         // [1024] log-density accumulator (pre-init = ldin)
{
  __shared__ __align__(16) char smem[25600];
  u16* sA = (u16*)smem;              // [256][32] bf16, slot-swizzled rows
  u16* sB = (u16*)(smem + 16384);    // [128][32] bf16 (rows >=96 are pad)
  float* sC = (float*)smem;          // [4 waves][16 rows][100] epilogue (reuses smem)

  const int tid  = threadIdx.x;
  const int lane = tid & 63;
  const int w    = tid >> 6;
  const int id   = blockIdx.x;
  const int work = ((id & 7) << 9) | (id >> 3);   // bijective, 4096 = 8*512
  const int m0   = (work & 3) << 8;               // 0,256,512,768
  const int nt   = work >> 2;                     // 0..1023
  const long n0  = (long)nt * 96;

  const int rA  = lane >> 2;
  // DMA source slot swizzle: row = 16c + rA, rho(row) = (row>>1)&3 = (lane>>3)&3
  const int cAs = (((lane & 3) ^ ((lane >> 3) & 3)) << 3);
  const int lr  = lane & 31, hi = lane >> 5;
  const int rho = (lr >> 1) & 3;                  // frag-read slot XOR (row%32 = lr)
  const int fr  = lane & 15, fq = lane >> 4;      // epilogue read-side mapping

  f32x16 acc[2][3];
  #pragma unroll
  for (int i=0;i<2;i++)
    #pragma unroll
    for (int j=0;j<3;j++)
      #pragma unroll
      for (int r=0;r<16;r++) acc[i][j][r] = 0.f;

  auto stage = [&](int kt){
    const int kofs = (kt << 5) + cAs;             // swizzled global slot
    #pragma unroll
    for (int cc = 0; cc < 4; ++cc){
      const int c = (w << 2) + cc;                         // 16 A chunks of 16 rows
      async16(sA + c*512, hmat + (long)(m0 + c*16 + rA)*512 + kofs);
    }
    #pragma unroll
    for (int cc = 0; cc < 2; ++cc){
      const int ch = (w << 1) + cc;                        // 8 B chunks (2 pad)
      int row = ch*16 + rA; if (row > 95) row = 95;        // clamp (pad rows never read)
      async16(sB + ch*512, w2t + (n0 + row)*512 + kofs);
    }
  };

  stage(0);
  for (int kt = 0; kt < 16; ++kt){
    asm volatile("s_waitcnt vmcnt(0)" ::: "memory");       // own DMA(kt) done
    __builtin_amdgcn_s_barrier();                          // -> all waves' DMA done
    // 32x32x16 fragments: A lane: row=lr (+rb*32), k=hi*8+j (+kh*16)
    //                     B lane: col=lr (+cb*32), k=hi*8+j (+kh*16)
    // LDS slot for logical slot s=(kh<<1)|hi is s^rho (inverse of DMA swizzle).
    bf16x8 af[2][2], bfv[3][2];
    #pragma unroll
    for (int rb=0; rb<2; ++rb)
      #pragma unroll
      for (int kh=0; kh<2; ++kh)
        af[rb][kh] = *(const bf16x8*)(sA + ((w<<6) + rb*32 + lr)*32 + ((((kh<<1)|hi) ^ rho)<<3));
    #pragma unroll
    for (int cb=0; cb<3; ++cb)
      #pragma unroll
      for (int kh=0; kh<2; ++kh)
        bfv[cb][kh] = *(const bf16x8*)(sB + (cb*32 + lr)*32 + ((((kh<<1)|hi) ^ rho)<<3));
    asm volatile("s_waitcnt lgkmcnt(0)" ::: "memory");     // own ds_reads landed
    __builtin_amdgcn_sched_barrier(0);                     // rule #18 fence
    __builtin_amdgcn_s_barrier();                          // -> LDS reusable
    if (kt < 15) stage(kt + 1);                            // DMA flies under MFMA
    __builtin_amdgcn_sched_barrier(0);                     // keep issue before MFMA
    #pragma unroll
    for (int rb=0; rb<2; ++rb)
      #pragma unroll
      for (int cb=0; cb<3; ++cb){
        acc[rb][cb] = __builtin_amdgcn_mfma_f32_32x32x16_bf16(af[rb][0], bfv[cb][0], acc[rb][cb], 0, 0, 0);
        acc[rb][cb] = __builtin_amdgcn_mfma_f32_32x32x16_bf16(af[rb][1], bfv[cb][1], acc[rb][cb], 0, 0, 0);
      }
  }

  // ---- epilogue: RAW acc+b2 -> LDS -> per-(b,s_out) spline ----
  // 32x32 C/D: col = lr, row(within rb*32) = (r&3) + 8*(r>>2) + 4*hi.
  // q = rb*2 + half covers contiguous rows [q*16, q*16+16):
  //   r = half*8 + rr, row16 = (rr&3) + 4*hi + 8*(rr>>2)  (bijective over rr,hi).
  // Read side (rows via fr, groups via fq) and spline math unchanged.
  const float shift = phase[0];
  float b2c[3];
  #pragma unroll
  for (int cb=0;cb<3;cb++) b2c[cb] = b2[n0 + cb*32 + lr];
  float* myC = sC + w*1600;                                // 16 rows x 100 floats

  #pragma unroll
  for (int q = 0; q < 4; ++q){
    const int rb = q >> 1;
    #pragma unroll
    for (int cb=0;cb<3;++cb)
      #pragma unroll
      for (int rr=0;rr<8;++rr){
        const int r = ((q & 1) << 3) + rr;
        const int row16 = (rr & 3) + (hi << 2) + ((rr >> 2) << 3);
        myC[row16*100 + cb*32 + lr] = acc[rb][cb][r] + b2c[cb];
      }

    const int row = fr;                 // 0..15 within quarter
    const int g   = fq;                 // s_out group 0..3
    const float* tp = myC + row*100 + g*24;
    float t[16];
    #pragma unroll
    for (int jj=0;jj<4;jj++){
      const f32x4 v = *(const f32x4*)(tp + 4*jj);
      t[4*jj] = v[0]; t[4*jj+1] = v[1]; t[4*jj+2] = v[2]; t[4*jj+3] = v[3];
    }

    const int bg = m0 + (w<<6) + (q<<4) + row;
    const int s  = (nt<<2) + g;
    const float x = x_in[(long)bg*4096 + s];

    // eh/ew = exp(tanh(raw)); sums raw (softmax normalization deferred)
    float eh[8], ew[8];
    float sh = 0.f, sw = 0.f;
    #pragma unroll
    for (int i=0;i<8;i++){ eh[i] = exp_tanh(t[i]);   sh += eh[i]; }
    #pragma unroll
    for (int i=0;i<8;i++){ ew[i] = exp_tanh(t[8+i]); sw += ew[i]; }

    // bin search in RAW cumsum space: cum_norm < x  <=>  cum_raw < x*sw/2pi
    const float xs = x * sw * (1.f / TWOPI_F);
    float cw = 0.f; int k = 0;
    #pragma unroll
    for (int i=0;i<8;i++){ cw += ew[i]; k += (cw < xs) ? 1 : 0; }
    if (k > 7) k = 7;

    // capture raw bin quantities (k=0: raw x_{k-1}=0; -EPS diff is ~1e-6-scale)
    float wkr = 0.f, hkr = 0.f, xkr = 0.f, phr = 0.f;
    float c2 = 0.f, h2 = 0.f;
    #pragma unroll
    for (int i=0;i<8;i++){
      if (i == k){ wkr = ew[i]; hkr = eh[i]; xkr = c2; phr = h2; }
      c2 += ew[i]; h2 += eh[i];
    }

    // only the 2 selected d values get tanh+softplus (runtime-indexed LDS read)
    const float* dp = tp + 16;
    const float th0 = tanh_nc(dp[k]);
    const float th1 = tanh_nc(dp[(k + 1) & 7]);
    const float dk  = __logf(1.f + __expf(th0));   // softplus, arg in (-1,1)
    const float dk1 = __logf(1.f + __expf(th1));

    const float rsh = rcpf(sh);
    const float rwk = rcpf(wkr);
    const float alpha = (xs - xkr) * rwk;          // == (x - x_{k-1})/w_k
    const float sk = hkr * rwk * (sw * rsh);       // == h_k/w_k
    const float hk = TWOPI_F * hkr * rsh;
    const float ph = TWOPI_F * phr * rsh;
    const float a1m = alpha * (1.f - alpha);
    const float denom = sk + (dk1 + dk - 2.f*sk)*a1m;
    const float rd = rcpf(denom);
    const float phiv = ph + hk*(sk*alpha*alpha + dk*a1m)*rd;
    float p = phiv + shift;                 // conditional subtract == mod
    if (p >= TWOPI_F) p -= TWOPI_F;
    if (p >= TWOPI_F) p -= TWOPI_F;
    phi_out[(long)bg*4096 + s] = p;

    const float om = 1.f - alpha;
    const float num = dk1*alpha*alpha + 2.f*sk*a1m + dk*om*om;
    const float srd = sk * rd;
    float lg = __logf(srd*srd*num);         // == log(sk^2*num/denom^2)
    lg += __shfl_xor(lg, 16);               // sum over the 4 s_out groups (same row)
    lg += __shfl_xor(lg, 32);
    if (lane < 16) atomicAdd(ld + bg, -lg); // device-scope, fire-and-forget
  }
}

extern "C" void kernel_launch(void* const* d_in, const int* in_sizes, int n_in,
                              void* d_out, int out_size, void* d_ws, size_t ws_size,
                              hipStream_t stream){
  (void)in_sizes; (void)n_in; (void)out_size; (void)ws_size;
  const float* x_in  = (const float*)d_in[0];
  const float* x_pas = (const float*)d_in[1];
  const float* ldin  = (const float*)d_in[2];
  const float* w1    = (const float*)d_in[3];
  const float* b1    = (const float*)d_in[4];
  const float* w2    = (const float*)d_in[5];
  const float* b2    = (const float*)d_in[6];
  const float* phase = (const float*)d_in[7];
  float* out   = (float*)d_out;
  float* phi   = out;
  float* ldout = out + (size_t)1024*4096;

  // workspace layout (needs ~118.5 MB)
  char* ws = (char*)d_ws;
  float* stats = (float*)ws;                       // 8 B
  u16* xn   = (u16*)(ws + 256);                    // 8 MB   [1024][4096] bf16
  u16* w1t  = (u16*)(ws + 8388864);                // 4 MB   [512][4096] bf16
  u16* hb   = (u16*)(ws + 12583168);               // 1 MB   [1024][512] bf16
  u16* w2t  = (u16*)(ws + 13631744);               // 96 MB  [98304][512] bf16
  float* part = (float*)(ws + 114295040);          // 4 MB   gemm1 split-K partials

  hipMemsetAsync(stats, 0, 8, stream);
  k_stats<<<1024, 256, 0, stream>>>(x_pas, stats, ldin, ldout);
  k_prep<<<2048, 256, 0, stream>>>(x_pas, stats, xn);
  k_transpose_cvt<<<dim3(16, 4),  256, 0, stream>>>(w1, w1t, 4096, 512);
  k_transpose_cvt<<<dim3(2, 768), 256, 0, stream>>>(w2, w2t, 512, 98304);
  k_gemm1<<<dim3(8, 16, 2), 256, 0, stream>>>(xn, w1t, part);
  k_gemm1b<<<512, 256, 0, stream>>>(part, b1, hb);
  k_gemm2<<<dim3(4096), 256, 0, stream>>>(hb, w2t, b2, x_in, phase, phi, ldout);
}

// Round 8
// 531.667 us; speedup vs baseline: 1.0582x; 1.0582x over previous
//
#include <hip/hip_runtime.h>
#include <cstdint>
#include <cstddef>

// ---------------------------------------------------------------------------
// CircularSplineLayer pipeline:
//  k_stats          global sum/sumsq of x_passive; also ldout = ldin (free)
//  k_prep           xn -> bf16 [1024][4096]
//  k_transpose_cvt  f32 [K][N] -> bf16 [N][K], 256x128 tiles, XOR-swizzled LDS
//  k_gemm1          split-K=2 MFMA bf16, 4-deep LDS ring + counted vmcnt
//  k_gemm1b         combine partials + bias + tanh -> h bf16 [1024][512]
//  k_gemm2          ROUND-6 K-loop verbatim: MFMA 16x16x32 tile 256x96 (acc in
//                   VGPRs -> 84 regs, ~30% occ; 32x32 puts acc in AGPRs ->
//                   184-reg quantum cliff, r7 disproved). Single-buffer LDS
//                   25600B, T14 issue-early split. XCD-chunked swizzle.
//                   Fused spline epilogue; log-density via device atomics;
//                   phi staged in LDS cols 96-99 -> float4 coalesced stores.
// ---------------------------------------------------------------------------

typedef unsigned short u16;
typedef __bf16 bf16x8 __attribute__((ext_vector_type(8)));
typedef float f32x4 __attribute__((ext_vector_type(4)));
typedef unsigned short u16x8 __attribute__((ext_vector_type(8)));
typedef unsigned short u16x4 __attribute__((ext_vector_type(4)));
typedef unsigned short u16x2 __attribute__((ext_vector_type(2)));

#define TWOPI_F 6.28318530717958647692f

static __device__ __forceinline__ u16 f32_to_bf16(float f){
  unsigned u = __builtin_bit_cast(unsigned, f);
  return (u16)((u + 0x7fffu + ((u >> 16) & 1u)) >> 16);   // RNE
}
static __device__ __forceinline__ void async16(void* lds, const void* g){
  // global->LDS DMA, 16B/lane; LDS dest = wave-uniform base + lane*16
  __builtin_amdgcn_global_load_lds((const __attribute__((address_space(1))) void*)g,
                                   (__attribute__((address_space(3))) void*)lds,
                                   16, 0, 0);
}
static __device__ __forceinline__ float rcpf(float x){ return __builtin_amdgcn_rcpf(x); }
static __device__ __forceinline__ float fast_tanh(float x){
  x = fminf(fmaxf(x, -15.f), 15.f);
  float e = __expf(2.f * x);
  return (e - 1.f) / (e + 1.f);
}
// clamp-free tanh: 1 - 2/(e^{2x}+1); inf-safe (rcp(inf)=0 -> 1, rcp(1)=1 -> -1)
static __device__ __forceinline__ float tanh_nc(float x){
  const float e2 = __expf(2.f * x);
  return 1.f - 2.f * rcpf(e2 + 1.f);
}
// exp(tanh(x)) fused, clamp-free
static __device__ __forceinline__ float exp_tanh(float x){
  const float e2 = __expf(2.f * x);
  const float u  = rcpf(e2 + 1.f);
  return __expf(1.f - 2.f * u);
}

// ---- global sum / sumsq of x_passive (4194304 f32); ldout init piggyback ----
__global__ void k_stats(const float* __restrict__ xp, float* __restrict__ stats,
                        const float* __restrict__ ldin, float* __restrict__ ldout){
  __shared__ float ss[4], sq[4];
  const int tid = threadIdx.x;
  if (tid == 0) ldout[blockIdx.x] = ldin[blockIdx.x];    // 1024 blocks == B
  const long gt = (long)blockIdx.x * 256 + tid;          // float4 index
  const float4* x4 = (const float4*)xp;
  float s = 0.f, q = 0.f;
  #pragma unroll
  for (int p = 0; p < 4; ++p){
    float4 v = x4[gt + (long)p * 262144];
    s += v.x + v.y + v.z + v.w;
    q += v.x*v.x + v.y*v.y + v.z*v.z + v.w*v.w;
  }
  #pragma unroll
  for (int off = 32; off; off >>= 1){
    s += __shfl_down(s, off);
    q += __shfl_down(q, off);
  }
  if ((tid & 63) == 0){ ss[tid>>6] = s; sq[tid>>6] = q; }
  __syncthreads();
  if (tid == 0){
    atomicAdd(stats,     ss[0]+ss[1]+ss[2]+ss[3]);
    atomicAdd(stats + 1, sq[0]+sq[1]+sq[2]+sq[3]);
  }
}

// ---- xn = (x - mean)*istd -> bf16 ----
__global__ void k_prep(const float* __restrict__ xp, const float* __restrict__ stats,
                       u16* __restrict__ xn){
  const long t = (long)blockIdx.x * 256 + threadIdx.x;   // 524288 threads, 8 elems each
  const float sum = stats[0], sq = stats[1];
  const float N = 4194304.f;
  const float mean = sum / N;
  const float istd = rsqrtf((sq - sum*sum/N) / (N - 1.f));  // ddof=1
  const float4* x4 = (const float4*)xp;
  const float4 a = x4[2*t], b = x4[2*t+1];
  u16x8 o;
  o[0]=f32_to_bf16((a.x-mean)*istd); o[1]=f32_to_bf16((a.y-mean)*istd);
  o[2]=f32_to_bf16((a.z-mean)*istd); o[3]=f32_to_bf16((a.w-mean)*istd);
  o[4]=f32_to_bf16((b.x-mean)*istd); o[5]=f32_to_bf16((b.y-mean)*istd);
  o[6]=f32_to_bf16((b.z-mean)*istd); o[7]=f32_to_bf16((b.w-mean)*istd);
  ((u16x8*)xn)[t] = o;
}

// ---- f32 [Kd][Nd] -> bf16 [Nd][Kd]; 256(k) x 128(n) tiles ----
// Store: k-pair P of row n lands at pair-position P ^ (sigma<<2), sigma=(n>>2)&7
// (an XOR on the pair-GROUP index P>>2). Read: pair-group lk is therefore at
// group-position lk ^ sigma. Global reads AND writes stay 512B-contiguous.
__global__ __launch_bounds__(256) void k_transpose_cvt(const float* __restrict__ in,
                                                       u16* __restrict__ out,
                                                       int Kd, int Nd){
  __shared__ __align__(16) u16 tT[128*256];
  const int tid = threadIdx.x;
  const long k0 = (long)blockIdx.x * 256, n0 = (long)blockIdx.y * 128;
  const int lam = tid & 31, g = tid >> 5;
  const int c = lam * 4;
  const int sig = (lam & 7) << 2;                 // (sigma)<<2, sigma=(n>>2)&7
  #pragma unroll
  for (int pass = 0; pass < 16; ++pass){
    const int P = pass*8 + g;                     // k-pair index 0..127
    const float4 f0 = *(const float4*)&in[(k0 + 2*P    )*Nd + n0 + c];
    const float4 f1 = *(const float4*)&in[(k0 + 2*P + 1)*Nd + n0 + c];
    const int pp = 2*(P ^ sig);
    *(u16x2*)&tT[(c    )*256 + pp] = u16x2{f32_to_bf16(f0.x), f32_to_bf16(f1.x)};
    *(u16x2*)&tT[(c + 1)*256 + pp] = u16x2{f32_to_bf16(f0.y), f32_to_bf16(f1.y)};
    *(u16x2*)&tT[(c + 2)*256 + pp] = u16x2{f32_to_bf16(f0.z), f32_to_bf16(f1.z)};
    *(u16x2*)&tT[(c + 3)*256 + pp] = u16x2{f32_to_bf16(f0.w), f32_to_bf16(f1.w)};
  }
  __syncthreads();
  const int w = tid >> 6, l = tid & 63;
  const int lh = l >> 5, lk = l & 31;
  #pragma unroll
  for (int it = 0; it < 16; ++it){
    const int n = (w << 5) + (it << 1) + lh;
    const int s2 = (n >> 2) & 7;                  // sigma (group-index XOR) — NOT <<2
    const u16x8 v = *(const u16x8*)&tT[n*256 + 8*(lk ^ s2)];
    *(u16x8*)&out[(n0 + n)*Kd + k0 + 8*lk] = v;
  }
}

// ---- GEMM1 split-K: partial = xn @ w1 over half of K. M=1024 N=512 ----
// 4-deep LDS ring, prefetch depth 2, counted vmcnt (2 DMA instrs/wave/stage).
__global__ __launch_bounds__(256, 2) void k_gemm1(
    const u16* __restrict__ xn,   // [1024][4096] bf16
    const u16* __restrict__ w1t,  // [512][4096] bf16 (n-major)
    float* __restrict__ pp)       // [2][1024][512] f32 partials
{
  __shared__ __align__(16) u16 sA[4][64*32];
  __shared__ __align__(16) u16 sB[4][64*32];
  const int tid = threadIdx.x, lane = tid & 63, w = tid >> 6;
  const int n0 = blockIdx.x << 6, m0 = blockIdx.y << 6;
  const int ks = blockIdx.z;
  const int wm = w >> 1, wn = w & 1;
  const int rA = lane >> 2, cA = (lane & 3) << 3;
  const int fr = lane & 15, fq = lane >> 4;
  const f32x4 z4 = {0.f, 0.f, 0.f, 0.f};
  f32x4 acc[2][2];
  #pragma unroll
  for (int i=0;i<2;i++){ acc[i][0] = z4; acc[i][1] = z4; }

  auto stage = [&](int kt){
    const int b = kt & 3;
    const int kofs = (ks << 11) + (kt << 5) + cA;
    async16(sA[b] + w*512, xn  + (long)(m0 + w*16 + rA)*4096 + kofs);
    async16(sB[b] + w*512, w1t + (long)(n0 + w*16 + rA)*4096 + kofs);
  };

  stage(0); stage(1);
  for (int kt = 0; kt < 64; ++kt){
    if (kt < 62){
      stage(kt + 2);
      asm volatile("s_waitcnt vmcnt(4)" ::: "memory");   // kt's 2 DMAs done
    } else if (kt == 62){
      asm volatile("s_waitcnt vmcnt(2)" ::: "memory");
    } else {
      asm volatile("s_waitcnt vmcnt(0)" ::: "memory");
    }
    __builtin_amdgcn_s_barrier();
    const int b = kt & 3;
    bf16x8 af[2], bfv[2];
    #pragma unroll
    for (int i=0;i<2;i++) af[i]  = *(const bf16x8*)(sA[b] + ((wm<<5) + i*16 + fr)*32 + (fq<<3));
    #pragma unroll
    for (int j=0;j<2;j++) bfv[j] = *(const bf16x8*)(sB[b] + ((wn<<5) + j*16 + fr)*32 + (fq<<3));
    #pragma unroll
    for (int i=0;i<2;i++)
      #pragma unroll
      for (int j=0;j<2;j++)
        acc[i][j] = __builtin_amdgcn_mfma_f32_16x16x32_bf16(af[i], bfv[j], acc[i][j], 0, 0, 0);
  }
  float* po = pp + ((size_t)ks << 19);
  #pragma unroll
  for (int i=0;i<2;i++)
    #pragma unroll
    for (int j=0;j<2;j++)
      #pragma unroll
      for (int r=0;r<4;r++){
        const int row = m0 + (wm<<5) + i*16 + (fq<<2) + r;   // C/D: row=(lane>>4)*4+reg
        const int col = n0 + (wn<<5) + j*16 + fr;            //      col=lane&15
        po[row*512 + col] = acc[i][j][r];
      }
}

// ---- combine split-K partials: h = tanh(p0+p1+b1) -> bf16 ----
__global__ void k_gemm1b(const float* __restrict__ pp, const float* __restrict__ b1,
                         u16* __restrict__ hb){
  const int t = blockIdx.x * 256 + threadIdx.x;    // 131072 float4 groups
  const float4 a = ((const float4*)pp)[t];
  const float4 b = ((const float4*)pp)[131072 + t];
  const float4 bb = ((const float4*)b1)[t & 127];
  u16x4 o;
  o[0] = f32_to_bf16(fast_tanh(a.x + b.x + bb.x));
  o[1] = f32_to_bf16(fast_tanh(a.y + b.y + bb.y));
  o[2] = f32_to_bf16(fast_tanh(a.z + b.z + bb.z));
  o[3] = f32_to_bf16(fast_tanh(a.w + b.w + bb.w));
  ((u16x4*)hb)[t] = o;
}

// ---- GEMM2 + spline epilogue: M=1024 N=98304 K=512, tile 256x96 ----
// 1-D grid 4096, bijective XCD-chunked swizzle: work = ((id&7)<<9)|(id>>3).
// Each XCD owns 512 consecutive works (m fastest) -> w2t strips L2-hit across
// the 4 m-tiles, x_in 128B lines fetched once.
// T14 per-kt async split (single buffer, no extra LDS/VGPR), round-6 verbatim:
//   vmcnt(0)+barrier / ds_read+lgkm+sched_barrier+barrier / stage(kt+1) / MFMA
__global__ __launch_bounds__(256, 2) void k_gemm2(
    const u16* __restrict__ hmat,   // [1024][512] bf16
    const u16* __restrict__ w2t,    // [98304][512] bf16 (n-major)
    const float* __restrict__ b2,
    const float* __restrict__ x_in, // [1024][4096]
    const float* __restrict__ phase,
    float* __restrict__ phi_out,    // [1024][4096]
    float* __restrict__ ld)         // [1024] log-density accumulator (pre-init = ldin)
{
  __shared__ __align__(16) char smem[25600];
  u16* sA = (u16*)smem;              // [256][32] bf16 staging
  u16* sB = (u16*)(smem + 16384);    // [128][32] bf16 (rows >=96 are pad)
  float* sC = (float*)smem;          // [4 waves][16 rows][100] epilogue (reuses smem)

  const int tid  = threadIdx.x;
  const int lane = tid & 63;
  const int w    = tid >> 6;
  const int id   = blockIdx.x;
  const int work = ((id & 7) << 9) | (id >> 3);   // bijective, 4096 = 8*512
  const int m0   = (work & 3) << 8;               // 0,256,512,768
  const int nt   = work >> 2;                     // 0..1023
  const long n0  = (long)nt * 96;

  const int rA = lane >> 2, cA = (lane & 3) << 3;
  const int fr = lane & 15, fq = lane >> 4;

  const f32x4 z4 = {0.f, 0.f, 0.f, 0.f};
  f32x4 acc[4][6];
  #pragma unroll
  for (int i=0;i<4;i++)
    #pragma unroll
    for (int j=0;j<6;j++) acc[i][j] = z4;

  auto stage = [&](int kt){
    const int kofs = (kt << 5) + cA;
    #pragma unroll
    for (int cc = 0; cc < 4; ++cc){
      const int c = (w << 2) + cc;                         // 16 A chunks of 16 rows
      async16(sA + c*512, hmat + (long)(m0 + c*16 + rA)*512 + kofs);
    }
    #pragma unroll
    for (int cc = 0; cc < 2; ++cc){
      const int ch = (w << 1) + cc;                        // 8 B chunks (2 pad)
      int row = ch*16 + rA; if (row > 95) row = 95;        // clamp into valid rows
      async16(sB + ch*512, w2t + (n0 + row)*512 + kofs);
    }
  };

  stage(0);
  for (int kt = 0; kt < 16; ++kt){
    asm volatile("s_waitcnt vmcnt(0)" ::: "memory");       // own DMA(kt) done
    __builtin_amdgcn_s_barrier();                          // -> all waves' DMA done
    bf16x8 af[4], bfv[6];
    #pragma unroll
    for (int i=0;i<4;i++)
      af[i] = *(const bf16x8*)(sA + ((w<<6) + i*16 + fr)*32 + (fq<<3));
    #pragma unroll
    for (int j=0;j<6;j++)
      bfv[j] = *(const bf16x8*)(sB + (j*16 + fr)*32 + (fq<<3));
    asm volatile("s_waitcnt lgkmcnt(0)" ::: "memory");     // own ds_reads landed
    __builtin_amdgcn_sched_barrier(0);                     // rule #18 fence
    __builtin_amdgcn_s_barrier();                          // -> LDS reusable
    if (kt < 15) stage(kt + 1);                            // DMA flies under MFMA
    __builtin_amdgcn_sched_barrier(0);                     // keep issue before MFMA
    #pragma unroll
    for (int i=0;i<4;i++)
      #pragma unroll
      for (int j=0;j<6;j++)
        acc[i][j] = __builtin_amdgcn_mfma_f32_16x16x32_bf16(af[i], bfv[j], acc[i][j], 0, 0, 0);
  }
  // barrier #2 of kt=15 guarantees every wave's LDS reads are done -> sC reuse safe

  // ---- epilogue: RAW acc+b2 -> LDS -> per-(b,s_out) spline ----
  // myC regions are wave-private: no barriers needed inside (same-wave DS ops
  // are processed in order by the DS pipe; harness-verified across 6 rounds).
  // phi staged into free cols 96..99 of each myC row -> 16 lanes store float4
  // (coalesced) instead of 64 scattered dwords.
  const float shift = phase[0];
  float b2c[6];
  #pragma unroll
  for (int j=0;j<6;j++) b2c[j] = b2[n0 + j*16 + fr];
  float* myC = sC + w*1600;                                // 16 rows x 100 floats

  #pragma unroll
  for (int q = 0; q < 4; ++q){                             // quarter = row-frag index
    #pragma unroll
    for (int j=0;j<6;j++)
      #pragma unroll
      for (int r=0;r<4;r++)
        myC[((fq<<2)+r)*100 + j*16 + fr] = acc[q][j][r] + b2c[j];

    const int row = fr;                 // 0..15 within quarter
    const int g   = fq;                 // s_out group 0..3
    const float* tp = myC + row*100 + g*24;
    float t[16];
    #pragma unroll
    for (int jj=0;jj<4;jj++){
      const f32x4 v = *(const f32x4*)(tp + 4*jj);
      t[4*jj] = v[0]; t[4*jj+1] = v[1]; t[4*jj+2] = v[2]; t[4*jj+3] = v[3];
    }

    const int bg = m0 + (w<<6) + (q<<4) + row;
    const int s  = (nt<<2) + g;
    const float x = x_in[(long)bg*4096 + s];

    // eh/ew = exp(tanh(raw)); sums raw (softmax normalization deferred)
    float eh[8], ew[8];
    float sh = 0.f, sw = 0.f;
    #pragma unroll
    for (int i=0;i<8;i++){ eh[i] = exp_tanh(t[i]);   sh += eh[i]; }
    #pragma unroll
    for (int i=0;i<8;i++){ ew[i] = exp_tanh(t[8+i]); sw += ew[i]; }

    // bin search in RAW cumsum space: cum_norm < x  <=>  cum_raw < x*sw/2pi
    const float xs = x * sw * (1.f / TWOPI_F);
    float cw = 0.f; int k = 0;
    #pragma unroll
    for (int i=0;i<8;i++){ cw += ew[i]; k += (cw < xs) ? 1 : 0; }
    if (k > 7) k = 7;

    // capture raw bin quantities (k=0: raw x_{k-1}=0; -EPS diff is ~1e-6-scale)
    float wkr = 0.f, hkr = 0.f, xkr = 0.f, phr = 0.f;
    float c2 = 0.f, h2 = 0.f;
    #pragma unroll
    for (int i=0;i<8;i++){
      if (i == k){ wkr = ew[i]; hkr = eh[i]; xkr = c2; phr = h2; }
      c2 += ew[i]; h2 += eh[i];
    }

    // only the 2 selected d values get tanh+softplus (runtime-indexed LDS read)
    const float* dp = tp + 16;
    const float th0 = tanh_nc(dp[k]);
    const float th1 = tanh_nc(dp[(k + 1) & 7]);
    const float dk  = __logf(1.f + __expf(th0));   // softplus, arg in (-1,1)
    const float dk1 = __logf(1.f + __expf(th1));

    const float rsh = rcpf(sh);
    const float rwk = rcpf(wkr);
    const float alpha = (xs - xkr) * rwk;          // == (x - x_{k-1})/w_k
    const float sk = hkr * rwk * (sw * rsh);       // == h_k/w_k
    const float hk = TWOPI_F * hkr * rsh;
    const float ph = TWOPI_F * phr * rsh;
    const float a1m = alpha * (1.f - alpha);
    const float denom = sk + (dk1 + dk - 2.f*sk)*a1m;
    const float rd = rcpf(denom);
    const float phiv = ph + hk*(sk*alpha*alpha + dk*a1m)*rd;
    float p = phiv + shift;                 // conditional subtract == mod
    if (p >= TWOPI_F) p -= TWOPI_F;
    if (p >= TWOPI_F) p -= TWOPI_F;
    myC[row*100 + 96 + g] = p;              // stage phi (cols 96..99 free)

    const float om = 1.f - alpha;
    const float num = dk1*alpha*alpha + 2.f*sk*a1m + dk*om*om;
    const float srd = sk * rd;
    float lg = __logf(srd*srd*num);         // == log(sk^2*num/denom^2)
    lg += __shfl_xor(lg, 16);               // sum over the 4 s_out groups (same row)
    lg += __shfl_xor(lg, 32);
    if (lane < 16){
      atomicAdd(ld + bg, -lg);              // device-scope, fire-and-forget
      const f32x4 pv = *(const f32x4*)(myC + lane*100 + 96);   // row = lane (==fr)
      const int bgr = m0 + (w<<6) + (q<<4) + lane;
      float4 o; o.x = pv[0]; o.y = pv[1]; o.z = pv[2]; o.w = pv[3];
      *(float4*)&phi_out[(long)bgr*4096 + (nt<<2)] = o;        // 16B coalesced
    }
  }
}

extern "C" void kernel_launch(void* const* d_in, const int* in_sizes, int n_in,
                              void* d_out, int out_size, void* d_ws, size_t ws_size,
                              hipStream_t stream){
  (void)in_sizes; (void)n_in; (void)out_size; (void)ws_size;
  const float* x_in  = (const float*)d_in[0];
  const float* x_pas = (const float*)d_in[1];
  const float* ldin  = (const float*)d_in[2];
  const float* w1    = (const float*)d_in[3];
  const float* b1    = (const float*)d_in[4];
  const float* w2    = (const float*)d_in[5];
  const float* b2    = (const float*)d_in[6];
  const float* phase = (const float*)d_in[7];
  float* out   = (float*)d_out;
  float* phi   = out;
  float* ldout = out + (size_t)1024*4096;

  // workspace layout (needs ~118.5 MB)
  char* ws = (char*)d_ws;
  float* stats = (float*)ws;                       // 8 B
  u16* xn   = (u16*)(ws + 256);                    // 8 MB   [1024][4096] bf16
  u16* w1t  = (u16*)(ws + 8388864);                // 4 MB   [512][4096] bf16
  u16* hb   = (u16*)(ws + 12583168);               // 1 MB   [1024][512] bf16
  u16* w2t  = (u16*)(ws + 13631744);               // 96 MB  [98304][512] bf16
  float* part = (float*)(ws + 114295040);          // 4 MB   gemm1 split-K partials

  hipMemsetAsync(stats, 0, 8, stream);
  k_stats<<<1024, 256, 0, stream>>>(x_pas, stats, ldin, ldout);
  k_prep<<<2048, 256, 0, stream>>>(x_pas, stats, xn);
  k_transpose_cvt<<<dim3(16, 4),  256, 0, stream>>>(w1, w1t, 4096, 512);
  k_transpose_cvt<<<dim3(2, 768), 256, 0, stream>>>(w2, w2t, 512, 98304);
  k_gemm1<<<dim3(8, 16, 2), 256, 0, stream>>>(xn, w1t, part);
  k_gemm1b<<<512, 256, 0, stream>>>(part, b1, hb);
  k_gemm2<<<dim3(4096), 256, 0, stream>>>(hb, w2t, b2, x_in, phase, phi, ldout);
}

// Round 9
// 529.523 us; speedup vs baseline: 1.0625x; 1.0040x over previous
//
#include <hip/hip_runtime.h>
#include <cstdint>
#include <cstddef>

// ---------------------------------------------------------------------------
// CircularSplineLayer pipeline:
//  k_stats          global sum/sumsq of x_passive; also ldout = ldin (free)
//  k_prep           xn -> bf16 [1024][4096]
//  k_transpose_cvt  f32 [K][N] -> bf16 [N][K], 256x128 tiles, XOR-swizzled LDS
//  k_gemm1          split-K=2 MFMA bf16, 4-deep LDS ring + counted vmcnt
//  k_gemm1b         combine partials + bias + tanh -> h bf16 [1024][512]
//  k_gemm2          R8 K-loop verbatim (16x16x32, T14 split, single-buffer
//                   25600B). NEW: __launch_bounds__(256,3) -- unified
//                   VGPR+AGPR budget 512/3=170; acc=96 AGPR, so arch side must
//                   fit ~74. Epilogue register-dieted to make that cheap:
//                   no eh/ew/t arrays, three capture-passes (monotone
//                   overwrite bin capture). Occupancy 2->3 waves/SIMD is the
//                   predicted +50% residency. Atomic log-density; phi staged
//                   in LDS cols 96-99 -> float4 coalesced stores.
// ---------------------------------------------------------------------------

typedef unsigned short u16;
typedef __bf16 bf16x8 __attribute__((ext_vector_type(8)));
typedef float f32x4 __attribute__((ext_vector_type(4)));
typedef unsigned short u16x8 __attribute__((ext_vector_type(8)));
typedef unsigned short u16x4 __attribute__((ext_vector_type(4)));
typedef unsigned short u16x2 __attribute__((ext_vector_type(2)));

#define TWOPI_F 6.28318530717958647692f

static __device__ __forceinline__ u16 f32_to_bf16(float f){
  unsigned u = __builtin_bit_cast(unsigned, f);
  return (u16)((u + 0x7fffu + ((u >> 16) & 1u)) >> 16);   // RNE
}
static __device__ __forceinline__ void async16(void* lds, const void* g){
  // global->LDS DMA, 16B/lane; LDS dest = wave-uniform base + lane*16
  __builtin_amdgcn_global_load_lds((const __attribute__((address_space(1))) void*)g,
                                   (__attribute__((address_space(3))) void*)lds,
                                   16, 0, 0);
}
static __device__ __forceinline__ float rcpf(float x){ return __builtin_amdgcn_rcpf(x); }
static __device__ __forceinline__ float fast_tanh(float x){
  x = fminf(fmaxf(x, -15.f), 15.f);
  float e = __expf(2.f * x);
  return (e - 1.f) / (e + 1.f);
}
// clamp-free tanh: 1 - 2/(e^{2x}+1); inf-safe (rcp(inf)=0 -> 1, rcp(1)=1 -> -1)
static __device__ __forceinline__ float tanh_nc(float x){
  const float e2 = __expf(2.f * x);
  return 1.f - 2.f * rcpf(e2 + 1.f);
}
// exp(tanh(x)) fused, clamp-free
static __device__ __forceinline__ float exp_tanh(float x){
  const float e2 = __expf(2.f * x);
  const float u  = rcpf(e2 + 1.f);
  return __expf(1.f - 2.f * u);
}

// ---- global sum / sumsq of x_passive (4194304 f32); ldout init piggyback ----
__global__ void k_stats(const float* __restrict__ xp, float* __restrict__ stats,
                        const float* __restrict__ ldin, float* __restrict__ ldout){
  __shared__ float ss[4], sq[4];
  const int tid = threadIdx.x;
  if (tid == 0) ldout[blockIdx.x] = ldin[blockIdx.x];    // 1024 blocks == B
  const long gt = (long)blockIdx.x * 256 + tid;          // float4 index
  const float4* x4 = (const float4*)xp;
  float s = 0.f, q = 0.f;
  #pragma unroll
  for (int p = 0; p < 4; ++p){
    float4 v = x4[gt + (long)p * 262144];
    s += v.x + v.y + v.z + v.w;
    q += v.x*v.x + v.y*v.y + v.z*v.z + v.w*v.w;
  }
  #pragma unroll
  for (int off = 32; off; off >>= 1){
    s += __shfl_down(s, off);
    q += __shfl_down(q, off);
  }
  if ((tid & 63) == 0){ ss[tid>>6] = s; sq[tid>>6] = q; }
  __syncthreads();
  if (tid == 0){
    atomicAdd(stats,     ss[0]+ss[1]+ss[2]+ss[3]);
    atomicAdd(stats + 1, sq[0]+sq[1]+sq[2]+sq[3]);
  }
}

// ---- xn = (x - mean)*istd -> bf16 ----
__global__ void k_prep(const float* __restrict__ xp, const float* __restrict__ stats,
                       u16* __restrict__ xn){
  const long t = (long)blockIdx.x * 256 + threadIdx.x;   // 524288 threads, 8 elems each
  const float sum = stats[0], sq = stats[1];
  const float N = 4194304.f;
  const float mean = sum / N;
  const float istd = rsqrtf((sq - sum*sum/N) / (N - 1.f));  // ddof=1
  const float4* x4 = (const float4*)xp;
  const float4 a = x4[2*t], b = x4[2*t+1];
  u16x8 o;
  o[0]=f32_to_bf16((a.x-mean)*istd); o[1]=f32_to_bf16((a.y-mean)*istd);
  o[2]=f32_to_bf16((a.z-mean)*istd); o[3]=f32_to_bf16((a.w-mean)*istd);
  o[4]=f32_to_bf16((b.x-mean)*istd); o[5]=f32_to_bf16((b.y-mean)*istd);
  o[6]=f32_to_bf16((b.z-mean)*istd); o[7]=f32_to_bf16((b.w-mean)*istd);
  ((u16x8*)xn)[t] = o;
}

// ---- f32 [Kd][Nd] -> bf16 [Nd][Kd]; 256(k) x 128(n) tiles ----
// Store: k-pair P of row n lands at pair-position P ^ (sigma<<2), sigma=(n>>2)&7
// (an XOR on the pair-GROUP index P>>2). Read: pair-group lk is therefore at
// group-position lk ^ sigma. Global reads AND writes stay 512B-contiguous.
__global__ __launch_bounds__(256) void k_transpose_cvt(const float* __restrict__ in,
                                                       u16* __restrict__ out,
                                                       int Kd, int Nd){
  __shared__ __align__(16) u16 tT[128*256];
  const int tid = threadIdx.x;
  const long k0 = (long)blockIdx.x * 256, n0 = (long)blockIdx.y * 128;
  const int lam = tid & 31, g = tid >> 5;
  const int c = lam * 4;
  const int sig = (lam & 7) << 2;                 // (sigma)<<2, sigma=(n>>2)&7
  #pragma unroll
  for (int pass = 0; pass < 16; ++pass){
    const int P = pass*8 + g;                     // k-pair index 0..127
    const float4 f0 = *(const float4*)&in[(k0 + 2*P    )*Nd + n0 + c];
    const float4 f1 = *(const float4*)&in[(k0 + 2*P + 1)*Nd + n0 + c];
    const int pp = 2*(P ^ sig);
    *(u16x2*)&tT[(c    )*256 + pp] = u16x2{f32_to_bf16(f0.x), f32_to_bf16(f1.x)};
    *(u16x2*)&tT[(c + 1)*256 + pp] = u16x2{f32_to_bf16(f0.y), f32_to_bf16(f1.y)};
    *(u16x2*)&tT[(c + 2)*256 + pp] = u16x2{f32_to_bf16(f0.z), f32_to_bf16(f1.z)};
    *(u16x2*)&tT[(c + 3)*256 + pp] = u16x2{f32_to_bf16(f0.w), f32_to_bf16(f1.w)};
  }
  __syncthreads();
  const int w = tid >> 6, l = tid & 63;
  const int lh = l >> 5, lk = l & 31;
  #pragma unroll
  for (int it = 0; it < 16; ++it){
    const int n = (w << 5) + (it << 1) + lh;
    const int s2 = (n >> 2) & 7;                  // sigma (group-index XOR) — NOT <<2
    const u16x8 v = *(const u16x8*)&tT[n*256 + 8*(lk ^ s2)];
    *(u16x8*)&out[(n0 + n)*Kd + k0 + 8*lk] = v;
  }
}

// ---- GEMM1 split-K: partial = xn @ w1 over half of K. M=1024 N=512 ----
// 4-deep LDS ring, prefetch depth 2, counted vmcnt (2 DMA instrs/wave/stage).
__global__ __launch_bounds__(256, 2) void k_gemm1(
    const u16* __restrict__ xn,   // [1024][4096] bf16
    const u16* __restrict__ w1t,  // [512][4096] bf16 (n-major)
    float* __restrict__ pp)       // [2][1024][512] f32 partials
{
  __shared__ __align__(16) u16 sA[4][64*32];
  __shared__ __align__(16) u16 sB[4][64*32];
  const int tid = threadIdx.x, lane = tid & 63, w = tid >> 6;
  const int n0 = blockIdx.x << 6, m0 = blockIdx.y << 6;
  const int ks = blockIdx.z;
  const int wm = w >> 1, wn = w & 1;
  const int rA = lane >> 2, cA = (lane & 3) << 3;
  const int fr = lane & 15, fq = lane >> 4;
  const f32x4 z4 = {0.f, 0.f, 0.f, 0.f};
  f32x4 acc[2][2];
  #pragma unroll
  for (int i=0;i<2;i++){ acc[i][0] = z4; acc[i][1] = z4; }

  auto stage = [&](int kt){
    const int b = kt & 3;
    const int kofs = (ks << 11) + (kt << 5) + cA;
    async16(sA[b] + w*512, xn  + (long)(m0 + w*16 + rA)*4096 + kofs);
    async16(sB[b] + w*512, w1t + (long)(n0 + w*16 + rA)*4096 + kofs);
  };

  stage(0); stage(1);
  for (int kt = 0; kt < 64; ++kt){
    if (kt < 62){
      stage(kt + 2);
      asm volatile("s_waitcnt vmcnt(4)" ::: "memory");   // kt's 2 DMAs done
    } else if (kt == 62){
      asm volatile("s_waitcnt vmcnt(2)" ::: "memory");
    } else {
      asm volatile("s_waitcnt vmcnt(0)" ::: "memory");
    }
    __builtin_amdgcn_s_barrier();
    const int b = kt & 3;
    bf16x8 af[2], bfv[2];
    #pragma unroll
    for (int i=0;i<2;i++) af[i]  = *(const bf16x8*)(sA[b] + ((wm<<5) + i*16 + fr)*32 + (fq<<3));
    #pragma unroll
    for (int j=0;j<2;j++) bfv[j] = *(const bf16x8*)(sB[b] + ((wn<<5) + j*16 + fr)*32 + (fq<<3));
    #pragma unroll
    for (int i=0;i<2;i++)
      #pragma unroll
      for (int j=0;j<2;j++)
        acc[i][j] = __builtin_amdgcn_mfma_f32_16x16x32_bf16(af[i], bfv[j], acc[i][j], 0, 0, 0);
  }
  float* po = pp + ((size_t)ks << 19);
  #pragma unroll
  for (int i=0;i<2;i++)
    #pragma unroll
    for (int j=0;j<2;j++)
      #pragma unroll
      for (int r=0;r<4;r++){
        const int row = m0 + (wm<<5) + i*16 + (fq<<2) + r;   // C/D: row=(lane>>4)*4+reg
        const int col = n0 + (wn<<5) + j*16 + fr;            //      col=lane&15
        po[row*512 + col] = acc[i][j][r];
      }
}

// ---- combine split-K partials: h = tanh(p0+p1+b1) -> bf16 ----
__global__ void k_gemm1b(const float* __restrict__ pp, const float* __restrict__ b1,
                         u16* __restrict__ hb){
  const int t = blockIdx.x * 256 + threadIdx.x;    // 131072 float4 groups
  const float4 a = ((const float4*)pp)[t];
  const float4 b = ((const float4*)pp)[131072 + t];
  const float4 bb = ((const float4*)b1)[t & 127];
  u16x4 o;
  o[0] = f32_to_bf16(fast_tanh(a.x + b.x + bb.x));
  o[1] = f32_to_bf16(fast_tanh(a.y + b.y + bb.y));
  o[2] = f32_to_bf16(fast_tanh(a.z + b.z + bb.z));
  o[3] = f32_to_bf16(fast_tanh(a.w + b.w + bb.w));
  ((u16x4*)hb)[t] = o;
}

// ---- GEMM2 + spline epilogue: M=1024 N=98304 K=512, tile 256x96 ----
// 1-D grid 4096, bijective XCD-chunked swizzle: work = ((id&7)<<9)|(id>>3).
// Each XCD owns 512 consecutive works (m fastest) -> w2t strips L2-hit across
// the 4 m-tiles, x_in 128B lines fetched once.
// T14 per-kt async split (single buffer), r6/r8 verbatim:
//   vmcnt(0)+barrier / ds_read+lgkm+sched_barrier+barrier / stage(kt+1) / MFMA
// __launch_bounds__(256,3): unified VGPR+AGPR budget 170/wave -> with acc=96
// AGPR the arch side must fit ~74 -> 3 waves/SIMD (was 2 at 84+96=180).
__global__ __launch_bounds__(256, 3) void k_gemm2(
    const u16* __restrict__ hmat,   // [1024][512] bf16
    const u16* __restrict__ w2t,    // [98304][512] bf16 (n-major)
    const float* __restrict__ b2,
    const float* __restrict__ x_in, // [1024][4096]
    const float* __restrict__ phase,
    float* __restrict__ phi_out,    // [1024][4096]
    float* __restrict__ ld)         // [1024] log-density accumulator (pre-init = ldin)
{
  __shared__ __align__(16) char smem[25600];
  u16* sA = (u16*)smem;              // [256][32] bf16 staging
  u16* sB = (u16*)(smem + 16384);    // [128][32] bf16 (rows >=96 are pad)
  float* sC = (float*)smem;          // [4 waves][16 rows][100] epilogue (reuses smem)

  const int tid  = threadIdx.x;
  const int lane = tid & 63;
  const int w    = tid >> 6;
  const int id   = blockIdx.x;
  const int work = ((id & 7) << 9) | (id >> 3);   // bijective, 4096 = 8*512
  const int m0   = (work & 3) << 8;               // 0,256,512,768
  const int nt   = work >> 2;                     // 0..1023
  const long n0  = (long)nt * 96;

  const int rA = lane >> 2, cA = (lane & 3) << 3;
  const int fr = lane & 15, fq = lane >> 4;

  const f32x4 z4 = {0.f, 0.f, 0.f, 0.f};
  f32x4 acc[4][6];
  #pragma unroll
  for (int i=0;i<4;i++)
    #pragma unroll
    for (int j=0;j<6;j++) acc[i][j] = z4;

  auto stage = [&](int kt){
    const int kofs = (kt << 5) + cA;
    #pragma unroll
    for (int cc = 0; cc < 4; ++cc){
      const int c = (w << 2) + cc;                         // 16 A chunks of 16 rows
      async16(sA + c*512, hmat + (long)(m0 + c*16 + rA)*512 + kofs);
    }
    #pragma unroll
    for (int cc = 0; cc < 2; ++cc){
      const int ch = (w << 1) + cc;                        // 8 B chunks (2 pad)
      int row = ch*16 + rA; if (row > 95) row = 95;        // clamp into valid rows
      async16(sB + ch*512, w2t + (n0 + row)*512 + kofs);
    }
  };

  stage(0);
  for (int kt = 0; kt < 16; ++kt){
    asm volatile("s_waitcnt vmcnt(0)" ::: "memory");       // own DMA(kt) done
    __builtin_amdgcn_s_barrier();                          // -> all waves' DMA done
    bf16x8 af[4], bfv[6];
    #pragma unroll
    for (int i=0;i<4;i++)
      af[i] = *(const bf16x8*)(sA + ((w<<6) + i*16 + fr)*32 + (fq<<3));
    #pragma unroll
    for (int j=0;j<6;j++)
      bfv[j] = *(const bf16x8*)(sB + (j*16 + fr)*32 + (fq<<3));
    asm volatile("s_waitcnt lgkmcnt(0)" ::: "memory");     // own ds_reads landed
    __builtin_amdgcn_sched_barrier(0);                     // rule #18 fence
    __builtin_amdgcn_s_barrier();                          // -> LDS reusable
    if (kt < 15) stage(kt + 1);                            // DMA flies under MFMA
    __builtin_amdgcn_sched_barrier(0);                     // keep issue before MFMA
    #pragma unroll
    for (int i=0;i<4;i++)
      #pragma unroll
      for (int j=0;j<6;j++)
        acc[i][j] = __builtin_amdgcn_mfma_f32_16x16x32_bf16(af[i], bfv[j], acc[i][j], 0, 0, 0);
  }
  // barrier #2 of kt=15 guarantees every wave's LDS reads are done -> sC reuse safe

  // ---- epilogue: RAW acc+b2 -> LDS -> per-(b,s_out) spline ----
  // myC regions are wave-private: no barriers needed inside (same-wave DS ops
  // are processed in order by the DS pipe; harness-verified across 7 rounds).
  // Register diet (for launch_bounds 3): no eh/ew/t arrays. Three passes:
  //  1) sw = sum exp_tanh(w_raw)            (no array)
  //  2) recompute ew on the fly; monotone-overwrite capture of k,wkr,xkr
  //     (k = max{j: S_j < xs}; forced capture at i=0 handles xs==0)
  //  3) eh on the fly, i==k capture of hkr,phr; sh = total
  const float shift = phase[0];
  float b2c[6];
  #pragma unroll
  for (int j=0;j<6;j++) b2c[j] = b2[n0 + j*16 + fr];
  float* myC = sC + w*1600;                                // 16 rows x 100 floats

  #pragma unroll
  for (int q = 0; q < 4; ++q){                             // quarter = row-frag index
    #pragma unroll
    for (int j=0;j<6;j++)
      #pragma unroll
      for (int r=0;r<4;r++)
        myC[((fq<<2)+r)*100 + j*16 + fr] = acc[q][j][r] + b2c[j];

    const int row = fr;                 // 0..15 within quarter
    const int g   = fq;                 // s_out group 0..3
    const float* tp = myC + row*100 + g*24;

    const int bg = m0 + (w<<6) + (q<<4) + row;
    const int s  = (nt<<2) + g;
    const float x = x_in[(long)bg*4096 + s];

    // pass 1: w_raw = tp[8..15]; sw (no array kept)
    const f32x4 w0 = *(const f32x4*)(tp + 8);
    const f32x4 w1 = *(const f32x4*)(tp + 12);
    float sw = 0.f;
    #pragma unroll
    for (int i=0;i<4;i++){ sw += exp_tanh(w0[i]); sw += exp_tanh(w1[i]); }

    // bin search in RAW cumsum space: cum_norm < x  <=>  cum_raw < x*sw/2pi
    const float xs = x * sw * (1.f / TWOPI_F);

    // pass 2: recompute ew, capture k / wkr / xkr by monotone overwrite
    float cw = 0.f, wkr = 0.f, xkr = 0.f; int k = 0;
    #pragma unroll
    for (int i=0;i<8;i++){
      const float e = exp_tanh(i < 4 ? w0[i] : w1[i-4]);
      if (cw < xs || i == 0){ k = i; wkr = e; xkr = cw; }
      cw += e;
    }

    // pass 3: h_raw = tp[0..7]; capture hkr / phr at i==k
    const f32x4 h0 = *(const f32x4*)(tp);
    const f32x4 h1 = *(const f32x4*)(tp + 4);
    float h2 = 0.f, hkr = 0.f, phr = 0.f;
    #pragma unroll
    for (int i=0;i<8;i++){
      const float e = exp_tanh(i < 4 ? h0[i] : h1[i-4]);
      if (i == k){ hkr = e; phr = h2; }
      h2 += e;
    }
    const float sh = h2;

    // only the 2 selected d values get tanh+softplus (runtime-indexed LDS read)
    const float* dp = tp + 16;
    const float th0 = tanh_nc(dp[k]);
    const float th1 = tanh_nc(dp[(k + 1) & 7]);
    const float dk  = __logf(1.f + __expf(th0));   // softplus, arg in (-1,1)
    const float dk1 = __logf(1.f + __expf(th1));

    const float rsh = rcpf(sh);
    const float rwk = rcpf(wkr);
    const float alpha = (xs - xkr) * rwk;          // == (x - x_{k-1})/w_k
    const float sk = hkr * rwk * (sw * rsh);       // == h_k/w_k
    const float hk = TWOPI_F * hkr * rsh;
    const float ph = TWOPI_F * phr * rsh;
    const float a1m = alpha * (1.f - alpha);
    const float denom = sk + (dk1 + dk - 2.f*sk)*a1m;
    const float rd = rcpf(denom);
    const float phiv = ph + hk*(sk*alpha*alpha + dk*a1m)*rd;
    float p = phiv + shift;                 // conditional subtract == mod
    if (p >= TWOPI_F) p -= TWOPI_F;
    if (p >= TWOPI_F) p -= TWOPI_F;
    myC[row*100 + 96 + g] = p;              // stage phi (cols 96..99 free)

    const float om = 1.f - alpha;
    const float num = dk1*alpha*alpha + 2.f*sk*a1m + dk*om*om;
    const float srd = sk * rd;
    float lg = __logf(srd*srd*num);         // == log(sk^2*num/denom^2)
    lg += __shfl_xor(lg, 16);               // sum over the 4 s_out groups (same row)
    lg += __shfl_xor(lg, 32);
    if (lane < 16){
      atomicAdd(ld + bg, -lg);              // device-scope, fire-and-forget
      const f32x4 pv = *(const f32x4*)(myC + lane*100 + 96);   // row = lane (==fr)
      const int bgr = m0 + (w<<6) + (q<<4) + lane;
      float4 o; o.x = pv[0]; o.y = pv[1]; o.z = pv[2]; o.w = pv[3];
      *(float4*)&phi_out[(long)bgr*4096 + (nt<<2)] = o;        // 16B coalesced
    }
  }
}

extern "C" void kernel_launch(void* const* d_in, const int* in_sizes, int n_in,
                              void* d_out, int out_size, void* d_ws, size_t ws_size,
                              hipStream_t stream){
  (void)in_sizes; (void)n_in; (void)out_size; (void)ws_size;
  const float* x_in  = (const float*)d_in[0];
  const float* x_pas = (const float*)d_in[1];
  const float* ldin  = (const float*)d_in[2];
  const float* w1    = (const float*)d_in[3];
  const float* b1    = (const float*)d_in[4];
  const float* w2    = (const float*)d_in[5];
  const float* b2    = (const float*)d_in[6];
  const float* phase = (const float*)d_in[7];
  float* out   = (float*)d_out;
  float* phi   = out;
  float* ldout = out + (size_t)1024*4096;

  // workspace layout (needs ~118.5 MB)
  char* ws = (char*)d_ws;
  float* stats = (float*)ws;                       // 8 B
  u16* xn   = (u16*)(ws + 256);                    // 8 MB   [1024][4096] bf16
  u16* w1t  = (u16*)(ws + 8388864);                // 4 MB   [512][4096] bf16
  u16* hb   = (u16*)(ws + 12583168);               // 1 MB   [1024][512] bf16
  u16* w2t  = (u16*)(ws + 13631744);               // 96 MB  [98304][512] bf16
  float* part = (float*)(ws + 114295040);          // 4 MB   gemm1 split-K partials

  hipMemsetAsync(stats, 0, 8, stream);
  k_stats<<<1024, 256, 0, stream>>>(x_pas, stats, ldin, ldout);
  k_prep<<<2048, 256, 0, stream>>>(x_pas, stats, xn);
  k_transpose_cvt<<<dim3(16, 4),  256, 0, stream>>>(w1, w1t, 4096, 512);
  k_transpose_cvt<<<dim3(2, 768), 256, 0, stream>>>(w2, w2t, 512, 98304);
  k_gemm1<<<dim3(8, 16, 2), 256, 0, stream>>>(xn, w1t, part);
  k_gemm1b<<<512, 256, 0, stream>>>(part, b1, hb);
  k_gemm2<<<dim3(4096), 256, 0, stream>>>(hb, w2t, b2, x_in, phase, phi, ldout);
}